// Round 5
// baseline (521.213 us; speedup 1.0000x reference)
//
#include <hip/hip_runtime.h>
#include <math.h>

// B=32, S=1024, D=512, F=8, KN=32 knots, H=8, hd=64. M = B*S = 32768 rows.

#define SOFF_SMEAN 2080
#define SOFF_SRSTD 3104
#define SOFF_G1    4128
#define SOFF_GB    4136
#define SOFF_SGB   4144
#define SOFF_QGB   4145
#define SOFF_G2    4160
#define SOFF_PART  4224

typedef short bf16x8_t __attribute__((ext_vector_type(8)));
typedef float f32x4_t __attribute__((ext_vector_type(4)));
typedef unsigned short us8_t __attribute__((ext_vector_type(8)));

__device__ __forceinline__ unsigned short f2bf(float f) {
  unsigned u = __float_as_uint(f);
  u = (u + 0x7FFFu + ((u >> 16) & 1u)) >> 16;
  return (unsigned short)u;
}
__device__ __forceinline__ float b2f(unsigned short u) {
  return __uint_as_float(((unsigned)u) << 16);
}

// ------------------------------------ prep: bf16 converts (x, 3 weights) + zero part
__global__ __launch_bounds__(256) void prep_kernel(const float* __restrict__ x,
    const float* __restrict__ in_w, const float* __restrict__ out_w,
    const float* __restrict__ outp_w, unsigned short* __restrict__ xb,
    unsigned short* __restrict__ wqkv, unsigned short* __restrict__ wout,
    unsigned short* __restrict__ woutp, float* __restrict__ part) {
  int b = blockIdx.x, t = threadIdx.x;
  const float* src; unsigned short* dst; int i;
  if (b < 8192)      { src = x;      dst = xb;    i = b * 256 + t; }
  else if (b < 8576) { src = in_w;   dst = wqkv;  i = (b - 8192) * 256 + t; }
  else if (b < 8704) { src = out_w;  dst = wout;  i = (b - 8576) * 256 + t; }
  else if (b < 8832) { src = outp_w; dst = woutp; i = (b - 8704) * 256 + t; }
  else { ((float4*)part)[(b - 8832) * 256 + t] = (float4){0.f, 0.f, 0.f, 0.f}; return; }
  float4 a = ((const float4*)src)[i * 2];
  float4 c = ((const float4*)src)[i * 2 + 1];
  us8_t o;
  o[0] = f2bf(a.x); o[1] = f2bf(a.y); o[2] = f2bf(a.z); o[3] = f2bf(a.w);
  o[4] = f2bf(c.x); o[5] = f2bf(c.y); o[6] = f2bf(c.z); o[7] = f2bf(c.w);
  *(us8_t*)(dst + (size_t)i * 8) = o;
}

// ------------------------------------------------- bf16 MFMA GEMM  C = A@B^T + bias
// 128x128 tile, BK=32, m97 structure + XOR bank swizzle:
// LDS slot s of row r holds k-chunk (s ^ ((r>>1)&3)); staging loads the permuted
// chunk on the GLOBAL side so the lane->LDS mapping stays contiguous (HW constraint).
// Fragment reads use offset ((chunk ^ ((fr>>1)&3))*8) -> 2-way bank aliasing (free).
template<int NT, bool OUT_BF16, bool STATS>
__global__ __launch_bounds__(256) void gemm_mfma_kernel(
    const unsigned short* __restrict__ A, const unsigned short* __restrict__ B,
    const float* __restrict__ bias, unsigned short* __restrict__ Cb,
    float* __restrict__ Cf, float* __restrict__ gstats, int N) {
  __shared__ unsigned short As[128 * 32];
  __shared__ unsigned short Bs[128 * 32];
  __shared__ float colred[256];
  const int bi = blockIdx.x;
  const int xcd = bi & 7, j = bi >> 3;
  const int m0 = (xcd * 32 + j / NT) * 128;
  const int n0 = (j % NT) * 128;
  const int t = threadIdx.x;
  const int w = t >> 6, lane = t & 63;
  const int wm = w >> 1, wn = w & 1;
  if (STATS) colred[t] = 0.f;
  f32x4_t acc[4][4];
#pragma unroll
  for (int i = 0; i < 4; ++i)
#pragma unroll
    for (int jj = 0; jj < 4; ++jj) acc[i][jj] = (f32x4_t){0.f, 0.f, 0.f, 0.f};

  const int lrow = lane >> 2;
  const int lk = (((lane & 3) ^ ((lane >> 3) & 3)) * 8);   // swizzled k-chunk
  const unsigned short* ga = A + (size_t)(m0 + w * 32 + lrow) * 512 + lk;
  const unsigned short* gb = B + (size_t)(n0 + w * 32 + lrow) * 512 + lk;
  unsigned short* lA = &As[(w * 32) * 32];
  unsigned short* lB = &Bs[(w * 32) * 32];
  const int fr = lane & 15;
  const int fo = ((((lane >> 4) & 3) ^ ((fr >> 1) & 3)) * 8);  // swizzled read offset

  for (int k0 = 0; k0 < 512; k0 += 32) {
    __syncthreads();
    __builtin_amdgcn_global_load_lds(
        (const __attribute__((address_space(1))) void*)(ga + k0),
        (__attribute__((address_space(3))) void*)lA, 16, 0, 0);
    __builtin_amdgcn_global_load_lds(
        (const __attribute__((address_space(1))) void*)(ga + k0 + 16 * 512),
        (__attribute__((address_space(3))) void*)(lA + 16 * 32), 16, 0, 0);
    __builtin_amdgcn_global_load_lds(
        (const __attribute__((address_space(1))) void*)(gb + k0),
        (__attribute__((address_space(3))) void*)lB, 16, 0, 0);
    __builtin_amdgcn_global_load_lds(
        (const __attribute__((address_space(1))) void*)(gb + k0 + 16 * 512),
        (__attribute__((address_space(3))) void*)(lB + 16 * 32), 16, 0, 0);
    __syncthreads();
    bf16x8_t af[4], bf[4];
#pragma unroll
    for (int mi = 0; mi < 4; ++mi)
      af[mi] = *(const bf16x8_t*)&As[(wm * 64 + mi * 16 + fr) * 32 + fo];
#pragma unroll
    for (int ni = 0; ni < 4; ++ni)
      bf[ni] = *(const bf16x8_t*)&Bs[(wn * 64 + ni * 16 + fr) * 32 + fo];
#pragma unroll
    for (int mi = 0; mi < 4; ++mi)
#pragma unroll
      for (int ni = 0; ni < 4; ++ni)
        acc[mi][ni] = __builtin_amdgcn_mfma_f32_16x16x32_bf16(af[mi], bf[ni], acc[mi][ni], 0, 0, 0);
  }
  // epilogue: C/D mapping col=lane&15, row=(lane>>4)*4+reg
  const int cr = (lane >> 4) * 4, cc = lane & 15;
#pragma unroll
  for (int ni = 0; ni < 4; ++ni) {
    int col = n0 + wn * 64 + ni * 16 + cc;
    float bv = bias[col];
    float lsum = 0.f, lsq = 0.f;
#pragma unroll
    for (int mi = 0; mi < 4; ++mi) {
#pragma unroll
      for (int jj = 0; jj < 4; ++jj) {
        int row = m0 + wm * 64 + mi * 16 + cr + jj;
        float v = acc[mi][ni][jj] + bv;
        if (OUT_BF16) Cb[(size_t)row * N + col] = f2bf(v);
        else          Cf[(size_t)row * N + col] = v;
        if (STATS) { lsum += v; lsq += v * v; }
      }
    }
    if (STATS) {
      lsum += __shfl_xor(lsum, 16); lsum += __shfl_xor(lsum, 32);
      lsq  += __shfl_xor(lsq, 16);  lsq  += __shfl_xor(lsq, 32);
      if (lane < 16) {
        int cidx = wn * 64 + ni * 16 + lane;
        atomicAdd(&colred[cidx], lsum);
        atomicAdd(&colred[128 + cidx], lsq);
      }
    }
  }
  if (STATS) {
    __syncthreads();
    if (t < 128) {
      atomicAdd(&gstats[n0 + t], colred[t]);
      atomicAdd(&gstats[512 + n0 + t], colred[128 + t]);
    }
  }
}

// ---------------------------------------------------------------- small attention
__global__ __launch_bounds__(256) void attn2_kernel(const unsigned short* __restrict__ qkv,
                                                    unsigned short* __restrict__ ctxb) {
  const int n = blockIdx.x, h = blockIdx.y, t = threadIdx.x;
  __shared__ float qs[32 * 68], ks[32 * 68], vs[32 * 68], ss[32 * 33];
  const int l = t >> 3, j0 = (t & 7) * 8;
  size_t rowb = ((size_t)(l * 1024 + n)) * 1536 + h * 64 + j0;
  us8_t qv = *(const us8_t*)(qkv + rowb);
  us8_t kv = *(const us8_t*)(qkv + rowb + 512);
  us8_t vv = *(const us8_t*)(qkv + rowb + 1024);
#pragma unroll
  for (int j = 0; j < 8; ++j) {
    qs[l * 68 + j0 + j] = b2f(qv[j]) * 0.125f;
    ks[l * 68 + j0 + j] = b2f(kv[j]);
    vs[l * 68 + j0 + j] = b2f(vv[j]);
  }
  __syncthreads();
  for (int o = t; o < 1024; o += 256) {
    int ll = o >> 5, m = o & 31;
    const float4* q4 = (const float4*)&qs[ll * 68];
    const float4* k4 = (const float4*)&ks[m * 68];
    float s = 0.f;
#pragma unroll
    for (int dd = 0; dd < 16; ++dd) {
      float4 a = q4[dd], b = k4[dd];
      s += a.x * b.x + a.y * b.y + a.z * b.z + a.w * b.w;
    }
    ss[ll * 33 + m] = s;
  }
  __syncthreads();
  if (t < 32) {
    float mx = -3e38f;
    for (int m = 0; m < 32; ++m) mx = fmaxf(mx, ss[t * 33 + m]);
    float sum = 0.f;
    for (int m = 0; m < 32; ++m) { float e = __expf(ss[t * 33 + m] - mx); ss[t * 33 + m] = e; sum += e; }
    float inv = 1.f / sum;
    for (int m = 0; m < 32; ++m) ss[t * 33 + m] *= inv;
  }
  __syncthreads();
  float o[8] = {0.f, 0.f, 0.f, 0.f, 0.f, 0.f, 0.f, 0.f};
#pragma unroll 8
  for (int m = 0; m < 32; ++m) {
    float pm = ss[l * 33 + m];
    const float* vr = &vs[m * 68 + j0];
#pragma unroll
    for (int j = 0; j < 8; ++j) o[j] += pm * vr[j];
  }
  us8_t ov;
#pragma unroll
  for (int j = 0; j < 8; ++j) ov[j] = f2bf(o[j]);
  *(us8_t*)(ctxb + ((size_t)(l * 1024 + n)) * 512 + h * 64 + j0) = ov;
}

// ------------------------ projection (M x 8), fp32 x, fused BN stats via atomics
__global__ __launch_bounds__(256) void proj_kernel(const float* __restrict__ x,
    const float* __restrict__ pw, const float* __restrict__ pb,
    float* __restrict__ p, float* __restrict__ partP) {
  int blk = blockIdx.x, t = threadIdx.x;
  int r0 = blk * 64;
  __shared__ float xsp[64 * 33];
  __shared__ float pwc[8 * 33];
  int l = t >> 2, fg = t & 3;
  float acc0 = 0.f, acc1 = 0.f;
  for (int k0 = 0; k0 < 512; k0 += 32) {
    __syncthreads();
    for (int i = t; i < 2048; i += 256) { int ll = i >> 5, kk = i & 31; xsp[ll * 33 + kk] = x[(size_t)(r0 + ll) * 512 + k0 + kk]; }
    { int ff = t >> 5, kk = t & 31; pwc[ff * 33 + kk] = pw[ff * 512 + k0 + kk]; }
    __syncthreads();
#pragma unroll 8
    for (int kk = 0; kk < 32; ++kk) {
      float xv = xsp[l * 33 + kk];
      acc0 += xv * pwc[(fg * 2) * 33 + kk];
      acc1 += xv * pwc[(fg * 2 + 1) * 33 + kk];
    }
  }
  float2 o; o.x = acc0 + pb[fg * 2]; o.y = acc1 + pb[fg * 2 + 1];
  *(float2*)&p[(r0 + l) * 8 + fg * 2] = o;
  // fused BN stats: reduce over the 64 rows of this block (stride-4 keeps fg aligned)
  __shared__ float r0s[256], r1s[256], q0s[256], q1s[256];
  r0s[t] = o.x; r1s[t] = o.y; q0s[t] = o.x * o.x; q1s[t] = o.y * o.y;
  __syncthreads();
  for (int off = 128; off >= 4; off >>= 1) {
    if (t < off) { r0s[t] += r0s[t + off]; r1s[t] += r1s[t + off];
                   q0s[t] += q0s[t + off]; q1s[t] += q1s[t + off]; }
    __syncthreads();
  }
  if (t < 4) {
    atomicAdd(&partP[t * 2],     r0s[t]); atomicAdd(&partP[t * 2 + 1],     r1s[t]);
    atomicAdd(&partP[8 + t * 2], q0s[t]); atomicAdd(&partP[8 + t * 2 + 1], q1s[t]);
  }
}

// --------------------- apply proj-BN in place (stats from partP) + min/max partials
__global__ __launch_bounds__(256) void bnminmax_kernel(float* __restrict__ p,
    const float* __restrict__ partP, const float* __restrict__ png,
    const float* __restrict__ pnb, float* __restrict__ partMM) {
  int t = threadIdx.x, blk = blockIdx.x;  // 64 blocks
  int i0 = blk * 256 + t;
  int f = i0 & 7;
  float pmean = partP[f] * (1.f / 32768.f);
  float prstd = rsqrtf(partP[8 + f] * (1.f / 32768.f) - pmean * pmean + 1e-5f);
  float k1 = prstd * png[f];
  float k0 = pnb[f] - pmean * k1;
  float mn = 3e38f, mx = -3e38f;
  for (int i = i0; i < 262144; i += 16384) {
    float v = p[i] * k1 + k0;
    p[i] = v;
    mn = fminf(mn, v); mx = fmaxf(mx, v);
  }
  __shared__ float rmn[256], rmx[256];
  rmn[t] = mn; rmx[t] = mx; __syncthreads();
  for (int off = 128; off >= 8; off >>= 1) {
    if (t < off) { rmn[t] = fminf(rmn[t], rmn[t + off]); rmx[t] = fmaxf(rmx[t], rmx[t + off]); }
    __syncthreads();
  }
  if (t < 8) { partMM[blk * 16 + t] = rmn[t]; partMM[blk * 16 + 8 + t] = rmx[t]; }
}

// ------------------------- spline (in place), folds min/max finalize from partMM
__global__ __launch_bounds__(256) void spline_kernel(float* __restrict__ p,
    const float* __restrict__ knots, const float* __restrict__ cps,
    const float* __restrict__ partMM) {
  __shared__ float ksh[8 * 33], csh[8 * 33];
  __shared__ float fmn[8], fmx[8];
  int t = threadIdx.x;
  { int f = t >> 5, j = t & 31; ksh[f * 33 + j] = knots[t]; csh[f * 33 + j] = cps[t]; }
  if (t < 8) {
    float mn = 3e38f, mx = -3e38f;
#pragma unroll
    for (int b = 0; b < 64; ++b) {
      mn = fminf(mn, partMM[b * 16 + t]);
      mx = fmaxf(mx, partMM[b * 16 + 8 + t]);
    }
    fmn[t] = mn; fmx[t] = mx;
  }
  __syncthreads();
  int i = blockIdx.x * 256 + t;
  int f = i & 7;
  float xv = p[i];
  float mn = fmn[f], mx = fmx[f];
  float xn = (xv - mn) / (mx - mn + 1e-6f);
  const float* kn = &ksh[f * 33];
  const float* cp = &csh[f * 33];
  int pcnt = 0;
#pragma unroll
  for (int j = 0; j < 32; ++j) pcnt += (kn[j] <= xn) ? 1 : 0;
  int idx = pcnt - 1;
  idx = idx < 0 ? 0 : (idx > 30 ? 30 : idx);
  float k0v = kn[idx], k1v = kn[idx + 1];
  float tt = (xn - k0v) / (k1v - k0v);
  float val = (1.f - tt) * cp[idx] + tt * cp[idx + 1];
  bool inr = (xn >= kn[0]) && (xn <= kn[31]);
  p[i] = inr ? val : 0.f;
}

// ------------------------------------------- gate-weight Grams (parallel, 88 blocks)
__global__ __launch_bounds__(256) void gateprep_kernel(const float* __restrict__ gw,
    const float* __restrict__ gb, float* __restrict__ stats) {
  int b = blockIdx.x, t = threadIdx.x;
  __shared__ float red[256];
  float s = 0.f;
  if (b < 64) {
    int f1 = b >> 3, f2 = b & 7;
    for (int j = t; j < 1024; j += 256) s += gw[j * 8 + f1] * gw[j * 8 + f2];
  } else if (b < 72) {
    int f = b - 64;
    for (int j = t; j < 1024; j += 256) s += gw[j * 8 + f];
  } else if (b < 80) {
    int f = b - 72;
    for (int j = t; j < 1024; j += 256) s += gb[j] * gw[j * 8 + f];
  } else if (b == 80) {
    for (int j = t; j < 1024; j += 256) s += gb[j];
  } else {
    for (int j = t; j < 1024; j += 256) s += gb[j] * gb[j];
  }
  red[t] = s; __syncthreads();
  for (int off = 128; off > 0; off >>= 1) { if (t < off) red[t] += red[t + off]; __syncthreads(); }
  if (t == 0) {
    float v = red[0];
    if (b < 64) stats[SOFF_G2 + b] = v;
    else if (b < 72) stats[SOFF_G1 + (b - 64)] = v;
    else if (b < 80) stats[SOFF_GB + (b - 72)] = v;
    else if (b == 80) stats[SOFF_SGB] = v;
    else stats[SOFF_QGB] = v;
  }
}

// -------------------------------------- per-s BN stats of h WITHOUT materializing h
__global__ __launch_bounds__(256) void sstats_kernel(const float* __restrict__ tbuf,
                                                     float* __restrict__ stats) {
  int s = blockIdx.x, t = threadIdx.x;
  __shared__ float tv[256];
  __shared__ float red[256];
  __shared__ float T1[8];
  __shared__ float Ms[64];
  int b = t >> 3, f = t & 7;
  tv[t] = tbuf[(b * 1024 + s) * 8 + f];
  __syncthreads();
  red[t] = tv[t]; __syncthreads();
  for (int off = 128; off >= 8; off >>= 1) { if (t < off) red[t] += red[t + off]; __syncthreads(); }
  if (t < 8) T1[t] = red[t];
  if (t < 64) {
    int f1 = t >> 3, f2 = t & 7; float sM = 0.f;
    for (int bb = 0; bb < 32; ++bb) sM += tv[bb * 8 + f1] * tv[bb * 8 + f2];
    Ms[t] = sM;
  }
  __syncthreads();
  if (t == 0) {
    float sh = 0.f, s2 = 0.f;
    for (int ff = 0; ff < 8; ++ff) {
      sh += stats[SOFF_G1 + ff] * T1[ff];
      s2 += 2.f * stats[SOFF_GB + ff] * T1[ff];
    }
    sh += 32.f * stats[SOFF_SGB];
    for (int i = 0; i < 64; ++i) s2 += Ms[i] * stats[SOFF_G2 + i];
    s2 += 32.f * stats[SOFF_QGB];
    float mean = sh / 32768.f;
    float var = s2 / 32768.f - mean * mean;
    stats[SOFF_SMEAN + s] = mean;
    stats[SOFF_SRSTD + s] = rsqrtf(var + 1e-5f);
  }
}

// ---- recompute h row (fp32 gate_w — MUST match sstats' weights), BN-s, GLU, LN
__global__ __launch_bounds__(256) void gluln_kernel(const float* __restrict__ tbuf,
    const float* __restrict__ gw, const float* __restrict__ gb,
    const float* __restrict__ stats, const float* __restrict__ gbng,
    const float* __restrict__ gbnb, const float* __restrict__ lng,
    const float* __restrict__ lnb, unsigned short* __restrict__ gatedb) {
  const int t = threadIdx.x, wave = t >> 6, lane = t & 63;
  for (int rr = 0; rr < 4; ++rr) {
    const int r = blockIdx.x * 16 + wave * 4 + rr;
    const int s = r & 1023;
    float4 tA = *(const float4*)&tbuf[r * 8];
    float4 tB = *(const float4*)&tbuf[r * 8 + 4];
    float smean = stats[SOFF_SMEAN + s], srstd = stats[SOFF_SRSTD + s];
    float k1 = srstd * gbng[s];
    float k0 = gbnb[s] - smean * k1;
    float g[8];
    float sum = 0.f, sq = 0.f;
#pragma unroll
    for (int i = 0; i < 8; ++i) {
      int c = i * 64 + lane;
      float4 wa0 = *(const float4*)&gw[c * 8];
      float4 wa1 = *(const float4*)&gw[c * 8 + 4];
      float4 wb0 = *(const float4*)&gw[(c + 512) * 8];
      float4 wb1 = *(const float4*)&gw[(c + 512) * 8 + 4];
      float ha = tA.x * wa0.x + tA.y * wa0.y + tA.z * wa0.z + tA.w * wa0.w
               + tB.x * wa1.x + tB.y * wa1.y + tB.z * wa1.z + tB.w * wa1.w + gb[c];
      float hb = tA.x * wb0.x + tA.y * wb0.y + tA.z * wb0.z + tA.w * wb0.w
               + tB.x * wb1.x + tB.y * wb1.y + tB.z * wb1.z + tB.w * wb1.w + gb[c + 512];
      ha = ha * k1 + k0;
      hb = hb * k1 + k0;
      float gv = ha / (1.f + __expf(-hb));
      g[i] = gv; sum += gv; sq += gv * gv;
    }
#pragma unroll
    for (int m = 32; m >= 1; m >>= 1) { sum += __shfl_xor(sum, m); sq += __shfl_xor(sq, m); }
    float mean = sum * (1.f / 512.f);
    float rstd = rsqrtf(sq * (1.f / 512.f) - mean * mean + 1e-5f);
#pragma unroll
    for (int i = 0; i < 8; ++i) {
      int c = i * 64 + lane;
      gatedb[(size_t)r * 512 + c] = f2bf((g[i] - mean) * rstd * lng[c] + lnb[c]);
    }
  }
}

// ----------------- final elementwise: folds BN finalize for attn & out columns
__global__ __launch_bounds__(256) void final_kernel(const unsigned short* __restrict__ xb,
    const float* __restrict__ attn, const float* __restrict__ outl,
    const float* __restrict__ partA, const float* __restrict__ partO,
    const float* __restrict__ ag, const float* __restrict__ ab,
    const float* __restrict__ og, const float* __restrict__ ob,
    float* __restrict__ y) {
  int idx = blockIdx.x * 256 + threadIdx.x;
  int c4 = (idx & 127) * 4;
  ushort4 xu = *(const ushort4*)&xb[(size_t)idx * 4];
  float4 av = ((const float4*)attn)[idx];
  float4 ov = ((const float4*)outl)[idx];
  float4 pa  = *(const float4*)&partA[c4];
  float4 pa2 = *(const float4*)&partA[512 + c4];
  float4 po  = *(const float4*)&partO[c4];
  float4 po2 = *(const float4*)&partO[512 + c4];
  float4 g1 = *(const float4*)&ag[c4];
  float4 b1 = *(const float4*)&ab[c4];
  float4 g2 = *(const float4*)&og[c4];
  float4 b2 = *(const float4*)&ob[c4];
  const float inv = 1.f / 32768.f;
  float am, ar, om, orr, o;
  float4 res;
  am = pa.x * inv; ar = rsqrtf(pa2.x * inv - am * am + 1e-5f);
  om = po.x * inv; orr = rsqrtf(po2.x * inv - om * om + 1e-5f);
  o = b2f(xu.x) + (av.x - am) * ar * g1.x + b1.x + (ov.x - om) * orr * g2.x + b2.x; res.x = o;
  am = pa.y * inv; ar = rsqrtf(pa2.y * inv - am * am + 1e-5f);
  om = po.y * inv; orr = rsqrtf(po2.y * inv - om * om + 1e-5f);
  o = b2f(xu.y) + (av.y - am) * ar * g1.y + b1.y + (ov.y - om) * orr * g2.y + b2.y; res.y = o;
  am = pa.z * inv; ar = rsqrtf(pa2.z * inv - am * am + 1e-5f);
  om = po.z * inv; orr = rsqrtf(po2.z * inv - om * om + 1e-5f);
  o = b2f(xu.z) + (av.z - am) * ar * g1.z + b1.z + (ov.z - om) * orr * g2.z + b2.z; res.z = o;
  am = pa.w * inv; ar = rsqrtf(pa2.w * inv - am * am + 1e-5f);
  om = po.w * inv; orr = rsqrtf(po2.w * inv - om * om + 1e-5f);
  o = b2f(xu.w) + (av.w - am) * ar * g1.w + b1.w + (ov.w - om) * orr * g2.w + b2.w; res.w = o;
  ((float4*)y)[idx] = res;
}

extern "C" void kernel_launch(void* const* d_in, const int* in_sizes, int n_in,
                              void* d_out, int out_size, void* d_ws, size_t ws_size,
                              hipStream_t stream) {
  (void)in_sizes; (void)n_in; (void)out_size; (void)ws_size;
  const float* x        = (const float*)d_in[0];
  const float* in_w     = (const float*)d_in[1];
  const float* in_b     = (const float*)d_in[2];
  const float* out_w    = (const float*)d_in[3];
  const float* out_b    = (const float*)d_in[4];
  const float* attn_g   = (const float*)d_in[5];
  const float* attn_bt  = (const float*)d_in[6];
  const float* proj_w   = (const float*)d_in[7];
  const float* proj_b   = (const float*)d_in[8];
  const float* pn_g     = (const float*)d_in[9];
  const float* pn_bt    = (const float*)d_in[10];
  const float* knots    = (const float*)d_in[11];
  const float* cps      = (const float*)d_in[12];
  const float* gate_w   = (const float*)d_in[13];
  const float* gate_b   = (const float*)d_in[14];
  const float* gbn_g    = (const float*)d_in[15];
  const float* gbn_bt   = (const float*)d_in[16];
  const float* ln_g     = (const float*)d_in[17];
  const float* ln_bt    = (const float*)d_in[18];
  const float* outp_w   = (const float*)d_in[19];
  const float* outp_b   = (const float*)d_in[20];
  const float* on_g     = (const float*)d_in[21];
  const float* on_bt    = (const float*)d_in[22];

  float* out = (float*)d_out;
  unsigned short* xb      = (unsigned short*)d_ws;      // 16777216
  unsigned short* qkv_b   = xb + 16777216;              // 50331648
  unsigned short* ctx_b   = qkv_b + 50331648;           // 16777216
  unsigned short* wqkv_b  = ctx_b + 16777216;           // 786432
  unsigned short* wout_b  = wqkv_b + 786432;            // 262144
  unsigned short* woutp_b = wout_b + 262144;            // 262144
  float* proj  = (float*)(woutp_b + 262144);            // 262144 floats
  float* stats = proj + 262144;
  float* part  = stats + SOFF_PART;                     // 4096 floats (zeroed in prep)
  float* partA  = part;                                 // 1024 (atomic col stats attn)
  float* partO  = part + 1024;                          // 1024 (atomic col stats out)
  float* partP  = part + 2048;                          // 16 (proj BN atomic stats)
  float* partMM = part + 3072;                          // 1024 (minmax partials)
  float* attnf = (float*)qkv_b;        // alias: qkv dead after attn2
  unsigned short* gated_b = ctx_b;     // alias: ctx dead after out-proj gemm (xb stays live for final)

  prep_kernel<<<dim3(8836), dim3(256), 0, stream>>>(x, in_w, out_w, outp_w,
                                                    xb, wqkv_b, wout_b, woutp_b, part);
  // qkv = x @ in_w^T + in_b -> bf16
  gemm_mfma_kernel<12, true, false><<<dim3(3072), dim3(256), 0, stream>>>(
      xb, wqkv_b, in_b, qkv_b, nullptr, nullptr, 1536);
  attn2_kernel<<<dim3(1024, 8), dim3(256), 0, stream>>>(qkv_b, ctx_b);
  // attn_lin = ctx @ out_w^T + out_b -> fp32 (+ fused column stats)
  gemm_mfma_kernel<4, false, true><<<dim3(1024), dim3(256), 0, stream>>>(
      ctx_b, wout_b, out_b, nullptr, attnf, partA, 512);
  proj_kernel<<<dim3(512), dim3(256), 0, stream>>>(x, proj_w, proj_b, proj, partP);
  bnminmax_kernel<<<dim3(64), dim3(256), 0, stream>>>(proj, partP, pn_g, pn_bt, partMM);
  spline_kernel<<<dim3(1024), dim3(256), 0, stream>>>(proj, knots, cps, partMM);
  gateprep_kernel<<<dim3(88), dim3(256), 0, stream>>>(gate_w, gate_b, stats);
  sstats_kernel<<<dim3(1024), dim3(256), 0, stream>>>(proj, stats);
  gluln_kernel<<<dim3(2048), dim3(256), 0, stream>>>(proj, gate_w, gate_b, stats,
                                                     gbn_g, gbn_bt, ln_g, ln_bt, gated_b);
  // out = gated @ outp_w^T + outp_b -> fp32 (+ fused column stats)
  gemm_mfma_kernel<4, false, true><<<dim3(1024), dim3(256), 0, stream>>>(
      gated_b, woutp_b, outp_b, nullptr, out, partO, 512);
  final_kernel<<<dim3(16384), dim3(256), 0, stream>>>(xb, attnf, out, partA, partO,
                                                      attn_g, attn_bt, on_g, on_bt, out);
}